// Round 1
// baseline (273.421 us; speedup 1.0000x reference)
//
#include <hip/hip_runtime.h>

#define BATCH 2
#define SEQL 1024
#define DMODEL 1024
#define DINNER 2048
#define DSTATE 16
#define DTRANK 64
#define NCH 64
#define LC 16   // SEQL / NCH

typedef short bf16x8 __attribute__((ext_vector_type(8)));
typedef float f32x4 __attribute__((ext_vector_type(4)));
typedef int i32x4 __attribute__((ext_vector_type(4)));

__device__ __forceinline__ unsigned short f2bf(float f) {
  unsigned u = __float_as_uint(f);
  return (unsigned short)((u + 0x7fffu + ((u >> 16) & 1u)) >> 16);
}
__device__ __forceinline__ float sigmoidf_(float x) { return 1.f / (1.f + __expf(-x)); }

// ---------------- Generic bf16 MFMA GEMM: C[M][N] = A[M][K] * Bt[N][K]^T ----------------
#define BM 128
#define BN 128
#define BK 32

__global__ __launch_bounds__(256) void k_gemm_bf16(
    const unsigned short* __restrict__ A,   // [M][K] bf16 bits
    const unsigned short* __restrict__ Bt,  // [N][K] bf16 bits (B transposed)
    float* __restrict__ C, int M, int N, int K)
{
  __shared__ unsigned short As[BM][BK + 8];
  __shared__ unsigned short Bs[BN][BK + 8];
  const int tid = threadIdx.x;
  const int wave = tid >> 6, lane = tid & 63;
  const int m0 = blockIdx.x * BM, n0 = blockIdx.y * BN;
  const int wr = (wave >> 1) * 64, wc = (wave & 1) * 64;
  const int srow = tid >> 1, scol = (tid & 1) * 16;
  const unsigned short* ga = A + (size_t)(m0 + srow) * K + scol;
  const unsigned short* gb = Bt + (size_t)(n0 + srow) * K + scol;
  f32x4 acc[4][4] = {};
  const int kk = (lane >> 4) * 8;
  const int fr = lane & 15;
  for (int k0 = 0; k0 < K; k0 += BK) {
    i32x4 a0 = *(const i32x4*)(ga + k0);
    i32x4 a1 = *(const i32x4*)(ga + k0 + 8);
    i32x4 b0 = *(const i32x4*)(gb + k0);
    i32x4 b1 = *(const i32x4*)(gb + k0 + 8);
    *(i32x4*)&As[srow][scol]     = a0;
    *(i32x4*)&As[srow][scol + 8] = a1;
    *(i32x4*)&Bs[srow][scol]     = b0;
    *(i32x4*)&Bs[srow][scol + 8] = b1;
    __syncthreads();
    bf16x8 af[4], bfv[4];
    #pragma unroll
    for (int i = 0; i < 4; ++i) af[i]  = *(const bf16x8*)&As[wr + i * 16 + fr][kk];
    #pragma unroll
    for (int i = 0; i < 4; ++i) bfv[i] = *(const bf16x8*)&Bs[wc + i * 16 + fr][kk];
    #pragma unroll
    for (int i = 0; i < 4; ++i)
      #pragma unroll
      for (int j = 0; j < 4; ++j)
        acc[i][j] = __builtin_amdgcn_mfma_f32_16x16x32_bf16(af[i], bfv[j], acc[i][j], 0, 0, 0);
    __syncthreads();
  }
  const int rr = (lane >> 4) * 4;
  #pragma unroll
  for (int i = 0; i < 4; ++i)
    #pragma unroll
    for (int j = 0; j < 4; ++j)
      #pragma unroll
      for (int r = 0; r < 4; ++r)
        C[(size_t)(m0 + wr + i * 16 + rr + r) * N + (n0 + wc + j * 16 + fr)] = acc[i][j][r];
}

// ---------------- fp32 -> bf16 flat convert ----------------
__global__ void k_f32_to_bf16(const float* __restrict__ in, unsigned short* __restrict__ out, int n)
{
  int i = (blockIdx.x * 256 + threadIdx.x) * 4;
  if (i >= n) return;
  float4 v = *(const float4*)(in + i);
  unsigned short tmp[4] = {f2bf(v.x), f2bf(v.y), f2bf(v.z), f2bf(v.w)};
  *(unsigned long long*)(out + i) = *(unsigned long long*)tmp;
}

// ---------------- LDS-tiled transpose + convert: src[R][C] f32 -> dst[C][R] bf16 ----------------
__global__ __launch_bounds__(256) void k_transpose_bf16(
    const float* __restrict__ src, unsigned short* __restrict__ dst, int R, int C)
{
  __shared__ float t[64][65];
  int bc = blockIdx.x * 64, br = blockIdx.y * 64;
  int tr = threadIdx.x >> 2;
  int tc = (threadIdx.x & 3) * 16;
  #pragma unroll
  for (int i = 0; i < 4; ++i) {
    float4 v = *(const float4*)(src + (size_t)(br + tr) * C + bc + tc + i * 4);
    t[tr][tc + i * 4 + 0] = v.x; t[tr][tc + i * 4 + 1] = v.y;
    t[tr][tc + i * 4 + 2] = v.z; t[tr][tc + i * 4 + 3] = v.w;
  }
  __syncthreads();
  unsigned short tmp[16];
  #pragma unroll
  for (int i = 0; i < 16; ++i) tmp[i] = f2bf(t[tc + i][tr]);
  unsigned short* dp = dst + (size_t)(bc + tr) * R + br + tc;
  *(i32x4*)dp = *(i32x4*)&tmp[0];
  *(i32x4*)(dp + 8) = *(i32x4*)&tmp[8];
}

// ---------------- W_x (2048x96) -> padded transposed bf16 [128][2048] ----------------
__global__ void k_wx_pad_t(const float* __restrict__ Wx, unsigned short* __restrict__ out)
{
  int idx = blockIdx.x * 256 + threadIdx.x;  // over 128*2048
  int k = idx & (DINNER - 1);
  int n = idx >> 11;
  float v = (n < 96) ? Wx[(size_t)k * 96 + n] : 0.f;
  out[idx] = f2bf(v);
}

// ---------------- depthwise conv4 + bias + SiLU ----------------
__global__ void k_conv_silu(const float* __restrict__ xz, const float* __restrict__ cw,
                            const float* __restrict__ cb, float* __restrict__ xc,
                            unsigned short* __restrict__ xcb)
{
  int idx = blockIdx.x * 256 + threadIdx.x;  // over B*L*DINNER
  int d = idx & (DINNER - 1);
  int bl = idx >> 11;
  int l = bl & (SEQL - 1);
  float s = cb[d];
  #pragma unroll
  for (int k = 0; k < 4; ++k) {
    int ll = l - 3 + k;
    if (ll >= 0) s += xz[(size_t)(bl - 3 + k) * (2 * DINNER) + d] * cw[d * 4 + k];
  }
  float r = s * sigmoidf_(s);
  xc[idx] = r;
  xcb[idx] = f2bf(r);
}

// ---------------- extract dt_raw (cols 0..63 of dbl[2048][128]) -> bf16 ----------------
__global__ void k_extract_dt(const float* __restrict__ dbl, unsigned short* __restrict__ dtraw)
{
  int idx = blockIdx.x * 256 + threadIdx.x;  // 2048*64
  int k = idx & 63;
  int rw = idx >> 6;
  dtraw[idx] = f2bf(dbl[(size_t)rw * 128 + k]);
}

// ---------------- scan pass A: per-chunk local scan, record h_end and prod(dA) ----------------
__global__ __launch_bounds__(256) void k_scan_A(
    const float* __restrict__ dtlin, const float* __restrict__ bdt,
    const float* __restrict__ xc, const float* __restrict__ dbl,
    const float* __restrict__ Alog,
    float* __restrict__ hend, float* __restrict__ aprod)
{
  int gid = blockIdx.x * 256 + threadIdx.x;  // over B*NCH*DINNER
  int d = gid & (DINNER - 1);
  int t = gid >> 11;
  int c = t & (NCH - 1);
  int b = t >> 6;
  float As[DSTATE];
  #pragma unroll
  for (int s = 0; s < DSTATE; ++s) As[s] = -__expf(Alog[d * DSTATE + s]);
  float h[DSTATE], Ap[DSTATE];
  #pragma unroll
  for (int s = 0; s < DSTATE; ++s) { h[s] = 0.f; Ap[s] = 1.f; }
  float bd = bdt[d];
  int r = b * SEQL + c * LC;
  for (int li = 0; li < LC; ++li, ++r) {
    float u = dtlin[(size_t)r * DINNER + d] + bd;
    float dt = log1pf(__expf(u));
    float xv = xc[(size_t)r * DINNER + d];
    float dtx = dt * xv;
    const float* bp = dbl + (size_t)r * 128 + 64;
    float Bv[16];
    *(float4*)&Bv[0]  = *(const float4*)(bp);
    *(float4*)&Bv[4]  = *(const float4*)(bp + 4);
    *(float4*)&Bv[8]  = *(const float4*)(bp + 8);
    *(float4*)&Bv[12] = *(const float4*)(bp + 12);
    #pragma unroll
    for (int s = 0; s < DSTATE; ++s) {
      float dA = __expf(dt * As[s]);
      h[s] = dA * h[s] + dtx * Bv[s];
      Ap[s] *= dA;
    }
  }
  size_t base = ((size_t)(b * NCH + c) * DSTATE) * DINNER + d;
  #pragma unroll
  for (int s = 0; s < DSTATE; ++s) {
    hend[base + (size_t)s * DINNER] = h[s];
    aprod[base + (size_t)s * DINNER] = Ap[s];
  }
}

// ---------------- scan pass B: sequential prefix over chunks ----------------
__global__ void k_scan_B(const float* __restrict__ hend, const float* __restrict__ aprod,
                         float* __restrict__ hin)
{
  int gid = blockIdx.x * 256 + threadIdx.x;  // B*DSTATE*DINNER = 65536
  int d = gid & (DINNER - 1);
  int s = (gid >> 11) & (DSTATE - 1);
  int b = gid >> 15;
  float h = 0.f;
  for (int c = 0; c < NCH; ++c) {
    size_t idx = ((size_t)(b * NCH + c) * DSTATE + s) * DINNER + d;
    hin[idx] = h;
    h = aprod[idx] * h + hend[idx];
  }
}

// ---------------- scan pass C: replay with correct h_in + fused epilogue ----------------
__global__ __launch_bounds__(256) void k_scan_C(
    const float* __restrict__ dtlin, const float* __restrict__ bdt,
    const float* __restrict__ xc, const float* __restrict__ dbl,
    const float* __restrict__ Alog, const float* __restrict__ hin,
    const float* __restrict__ Dskip, const float* __restrict__ xz,
    unsigned short* __restrict__ yact)
{
  int gid = blockIdx.x * 256 + threadIdx.x;
  int d = gid & (DINNER - 1);
  int t = gid >> 11;
  int c = t & (NCH - 1);
  int b = t >> 6;
  float As[DSTATE];
  #pragma unroll
  for (int s = 0; s < DSTATE; ++s) As[s] = -__expf(Alog[d * DSTATE + s]);
  float h[DSTATE];
  size_t base = ((size_t)(b * NCH + c) * DSTATE) * DINNER + d;
  #pragma unroll
  for (int s = 0; s < DSTATE; ++s) h[s] = hin[base + (size_t)s * DINNER];
  float bd = bdt[d];
  float dsk = Dskip[d];
  int r = b * SEQL + c * LC;
  for (int li = 0; li < LC; ++li, ++r) {
    float u = dtlin[(size_t)r * DINNER + d] + bd;
    float dt = log1pf(__expf(u));
    float xv = xc[(size_t)r * DINNER + d];
    float dtx = dt * xv;
    const float* bp = dbl + (size_t)r * 128 + 64;
    float Bv[16], Cv[16];
    *(float4*)&Bv[0]  = *(const float4*)(bp);
    *(float4*)&Bv[4]  = *(const float4*)(bp + 4);
    *(float4*)&Bv[8]  = *(const float4*)(bp + 8);
    *(float4*)&Bv[12] = *(const float4*)(bp + 12);
    *(float4*)&Cv[0]  = *(const float4*)(bp + 16);
    *(float4*)&Cv[4]  = *(const float4*)(bp + 20);
    *(float4*)&Cv[8]  = *(const float4*)(bp + 24);
    *(float4*)&Cv[12] = *(const float4*)(bp + 28);
    float y = 0.f;
    #pragma unroll
    for (int s = 0; s < DSTATE; ++s) {
      float dA = __expf(dt * As[s]);
      h[s] = dA * h[s] + dtx * Bv[s];
      y += h[s] * Cv[s];
    }
    y += xv * dsk;
    float zv = xz[(size_t)r * (2 * DINNER) + DINNER + d];
    float ya = y * (zv * sigmoidf_(zv));
    yact[(size_t)r * DINNER + d] = f2bf(ya);
  }
}

extern "C" void kernel_launch(void* const* d_in, const int* in_sizes, int n_in,
                              void* d_out, int out_size, void* d_ws, size_t ws_size,
                              hipStream_t stream) {
  const float* x     = (const float*)d_in[0];
  const float* Win   = (const float*)d_in[1];
  const float* cw    = (const float*)d_in[2];
  const float* cbias = (const float*)d_in[3];
  const float* Wx    = (const float*)d_in[4];
  const float* Wdt   = (const float*)d_in[5];
  const float* bdt   = (const float*)d_in[6];
  const float* Alog  = (const float*)d_in[7];
  const float* Dsk   = (const float*)d_in[8];
  const float* Wout  = (const float*)d_in[9];
  float* out = (float*)d_out;

  char* ws = (char*)d_ws;
  size_t o = 0;
  auto alloc = [&](size_t bytes) { char* p = ws + o; o += (bytes + 255) & ~(size_t)255; return p; };
  float*          xz    = (float*)         alloc((size_t)2048 * 4096 * 4);
  unsigned short* xbf   = (unsigned short*)alloc((size_t)2048 * 1024 * 2);
  unsigned short* wint  = (unsigned short*)alloc((size_t)4096 * 1024 * 2);
  float*          xc    = (float*)         alloc((size_t)2048 * 2048 * 4);
  unsigned short* xcb   = (unsigned short*)alloc((size_t)2048 * 2048 * 2);
  unsigned short* wxt   = (unsigned short*)alloc((size_t)128  * 2048 * 2);
  float*          dbl   = (float*)         alloc((size_t)2048 * 128  * 4);
  unsigned short* dtraw = (unsigned short*)alloc((size_t)2048 * 64   * 2);
  unsigned short* wdtt  = (unsigned short*)alloc((size_t)2048 * 64   * 2);
  float*          dtlin = (float*)         alloc((size_t)2048 * 2048 * 4);
  float*          hend  = (float*)         alloc((size_t)2 * NCH * DSTATE * DINNER * 4);
  float*          aprod = (float*)         alloc((size_t)2 * NCH * DSTATE * DINNER * 4);
  float*          hin   = (float*)         alloc((size_t)2 * NCH * DSTATE * DINNER * 4);
  unsigned short* yact  = (unsigned short*)alloc((size_t)2048 * 2048 * 2);
  unsigned short* woutt = (unsigned short*)alloc((size_t)1024 * 2048 * 2);
  (void)ws_size; (void)in_sizes; (void)n_in; (void)out_size;

  // convert x -> bf16
  k_f32_to_bf16<<<2048, 256, 0, stream>>>(x, xbf, 2048 * 1024);
  // transpose+convert weights
  k_transpose_bf16<<<dim3(64, 16), 256, 0, stream>>>(Win,  wint,  1024, 4096);  // [4096][1024]
  k_transpose_bf16<<<dim3(16, 32), 256, 0, stream>>>(Wout, woutt, 2048, 1024);  // [1024][2048]
  k_transpose_bf16<<<dim3(32, 1),  256, 0, stream>>>(Wdt,  wdtt,  64,   2048);  // [2048][64]
  k_wx_pad_t<<<1024, 256, 0, stream>>>(Wx, wxt);                                // [128][2048]

  // GEMM1: xz = x @ W_in   (M=2048, N=4096, K=1024)
  k_gemm_bf16<<<dim3(16, 32), 256, 0, stream>>>(xbf, wint, xz, 2048, 4096, 1024);
  // conv + SiLU
  k_conv_silu<<<16384, 256, 0, stream>>>(xz, cw, cbias, xc, xcb);
  // GEMM2: dbl = xc @ W_x_pad  (M=2048, N=128, K=2048)
  k_gemm_bf16<<<dim3(16, 1), 256, 0, stream>>>(xcb, wxt, dbl, 2048, 128, 2048);
  // dt_raw extract
  k_extract_dt<<<512, 256, 0, stream>>>(dbl, dtraw);
  // GEMM3: dtlin = dt_raw @ W_dt  (M=2048, N=2048, K=64)
  k_gemm_bf16<<<dim3(16, 16), 256, 0, stream>>>(dtraw, wdtt, dtlin, 2048, 2048, 64);
  // chunked scan
  k_scan_A<<<1024, 256, 0, stream>>>(dtlin, bdt, xc, dbl, Alog, hend, aprod);
  k_scan_B<<<256, 256, 0, stream>>>(hend, aprod, hin);
  k_scan_C<<<1024, 256, 0, stream>>>(dtlin, bdt, xc, dbl, Alog, hin, Dsk, xz, yact);
  // GEMM5: out = y_act @ W_out  (M=2048, N=1024, K=2048)
  k_gemm_bf16<<<dim3(16, 8), 256, 0, stream>>>(yact, woutt, out, 2048, 1024, 2048);
}

// Round 2
// 211.624 us; speedup vs baseline: 1.2920x; 1.2920x over previous
//
#include <hip/hip_runtime.h>

#define BATCH 2
#define SEQL 1024
#define DMODEL 1024
#define DINNER 2048
#define DSTATE 16
#define DTRANK 64
#define NCH 64
#define LC 16   // SEQL / NCH

typedef short bf16x8 __attribute__((ext_vector_type(8)));
typedef float f32x4 __attribute__((ext_vector_type(4)));
typedef int i32x4 __attribute__((ext_vector_type(4)));

__device__ __forceinline__ unsigned short f2bf(float f) {
  unsigned u = __float_as_uint(f);
  return (unsigned short)((u + 0x7fffu + ((u >> 16) & 1u)) >> 16);
}
__device__ __forceinline__ float sigmoidf_(float x) { return 1.f / (1.f + __expf(-x)); }

__device__ __forceinline__ void gl_lds16(const unsigned short* g, unsigned short* l) {
  __builtin_amdgcn_global_load_lds(
      (const __attribute__((address_space(1))) unsigned int*)g,
      (__attribute__((address_space(3))) unsigned int*)l, 16, 0, 0);
}

// ---------------- m97-structure bf16 MFMA GEMM: C[M][N] (+)= A[M][K] * Bt[N][K]^T ----------------
// 128x128 tile, BK=64, global_load_lds width-16, XOR-swizzled LDS (linear dest,
// inverse-swizzled global source, swizzled ds_read). Split-K via gridDim.z (atomicAdd).
#define BM 128
#define BN 128

__global__ __launch_bounds__(256) void k_gemm_mfma(
    const unsigned short* __restrict__ A,   // [M][K] bf16 bits
    const unsigned short* __restrict__ Bt,  // [N][K] bf16 bits
    float* __restrict__ C, int M, int N, int K)
{
  __shared__ __attribute__((aligned(16))) unsigned short As[128 * 64];
  __shared__ __attribute__((aligned(16))) unsigned short Bs[128 * 64];
  const int tid = threadIdx.x;
  const int wave = tid >> 6, lane = tid & 63;
  const int m0 = blockIdx.x * BM, n0 = blockIdx.y * BN;
  const int Kc = K / gridDim.z;
  const int k0beg = blockIdx.z * Kc;
  const int wr = (wave >> 1) * 64, wc = (wave & 1) * 64;
  const int fr = lane & 15;
  const int qw = lane >> 4;

  // staging source mapping (constant per lane): chunk i covers LDS bytes
  // [wave*4096 + i*1024 + lane*16 .. +16). inverse-swizzle the global column.
  int srow[4], scol[4];
  #pragma unroll
  for (int i = 0; i < 4; ++i) {
    int off = wave * 4096 + i * 1024 + lane * 16;
    int row = off >> 7;                       // 128 B per row (64 bf16)
    int c16 = ((off >> 4) & 7) ^ (row & 7);   // inverse XOR swizzle
    srow[i] = row;
    scol[i] = c16 * 8;                        // in shorts
  }

  f32x4 acc[4][4] = {};
  for (int k0 = k0beg; k0 < k0beg + Kc; k0 += 64) {
    #pragma unroll
    for (int i = 0; i < 4; ++i)
      gl_lds16(A + (size_t)(m0 + srow[i]) * K + k0 + scol[i],
               &As[(wave * 4096 + i * 1024) >> 1]);
    #pragma unroll
    for (int i = 0; i < 4; ++i)
      gl_lds16(Bt + (size_t)(n0 + srow[i]) * K + k0 + scol[i],
               &Bs[(wave * 4096 + i * 1024) >> 1]);
    __syncthreads();
    #pragma unroll
    for (int t = 0; t < 2; ++t) {
      bf16x8 af[4], bfv[4];
      #pragma unroll
      for (int i = 0; i < 4; ++i) {
        int row = wr + i * 16 + fr;
        int c16 = (t * 4 + qw) ^ (row & 7);   // swizzled read
        af[i] = *(const bf16x8*)&As[row * 64 + c16 * 8];
      }
      #pragma unroll
      for (int j = 0; j < 4; ++j) {
        int row = wc + j * 16 + fr;
        int c16 = (t * 4 + qw) ^ (row & 7);
        bfv[j] = *(const bf16x8*)&Bs[row * 64 + c16 * 8];
      }
      #pragma unroll
      for (int i = 0; i < 4; ++i)
        #pragma unroll
        for (int j = 0; j < 4; ++j)
          acc[i][j] = __builtin_amdgcn_mfma_f32_16x16x32_bf16(af[i], bfv[j], acc[i][j], 0, 0, 0);
    }
    __syncthreads();
  }
  const int rr = qw * 4;
  if (gridDim.z == 1) {
    #pragma unroll
    for (int i = 0; i < 4; ++i)
      #pragma unroll
      for (int j = 0; j < 4; ++j)
        #pragma unroll
        for (int r = 0; r < 4; ++r)
          C[(size_t)(m0 + wr + i * 16 + rr + r) * N + (n0 + wc + j * 16 + fr)] = acc[i][j][r];
  } else {
    #pragma unroll
    for (int i = 0; i < 4; ++i)
      #pragma unroll
      for (int j = 0; j < 4; ++j)
        #pragma unroll
        for (int r = 0; r < 4; ++r)
          atomicAdd(&C[(size_t)(m0 + wr + i * 16 + rr + r) * N + (n0 + wc + j * 16 + fr)],
                    acc[i][j][r]);
  }
}

// ---------------- fp32 -> bf16 flat convert ----------------
__global__ void k_f32_to_bf16(const float* __restrict__ in, unsigned short* __restrict__ out, int n)
{
  int i = (blockIdx.x * 256 + threadIdx.x) * 4;
  if (i >= n) return;
  float4 v = *(const float4*)(in + i);
  unsigned short tmp[4] = {f2bf(v.x), f2bf(v.y), f2bf(v.z), f2bf(v.w)};
  *(unsigned long long*)(out + i) = *(unsigned long long*)tmp;
}

// ---------------- LDS-tiled transpose + convert: src[R][C] f32 -> dst[C][R] bf16 ----------------
__global__ __launch_bounds__(256) void k_transpose_bf16(
    const float* __restrict__ src, unsigned short* __restrict__ dst, int R, int C)
{
  __shared__ float t[64][65];
  int bc = blockIdx.x * 64, br = blockIdx.y * 64;
  int tr = threadIdx.x >> 2;
  int tc = (threadIdx.x & 3) * 16;
  #pragma unroll
  for (int i = 0; i < 4; ++i) {
    float4 v = *(const float4*)(src + (size_t)(br + tr) * C + bc + tc + i * 4);
    t[tr][tc + i * 4 + 0] = v.x; t[tr][tc + i * 4 + 1] = v.y;
    t[tr][tc + i * 4 + 2] = v.z; t[tr][tc + i * 4 + 3] = v.w;
  }
  __syncthreads();
  unsigned short tmp[16];
  #pragma unroll
  for (int i = 0; i < 16; ++i) tmp[i] = f2bf(t[tc + i][tr]);
  unsigned short* dp = dst + (size_t)(bc + tr) * R + br + tc;
  *(i32x4*)dp = *(i32x4*)&tmp[0];
  *(i32x4*)(dp + 8) = *(i32x4*)&tmp[8];
}

// ---------------- W_x (2048x96) -> padded transposed bf16 [128][2048] ----------------
__global__ void k_wx_pad_t(const float* __restrict__ Wx, unsigned short* __restrict__ out)
{
  int idx = blockIdx.x * 256 + threadIdx.x;  // over 128*2048
  int k = idx & (DINNER - 1);
  int n = idx >> 11;
  float v = (n < 96) ? Wx[(size_t)k * 96 + n] : 0.f;
  out[idx] = f2bf(v);
}

// ---------------- depthwise conv4 + bias + SiLU ----------------
__global__ void k_conv_silu(const float* __restrict__ xz, const float* __restrict__ cw,
                            const float* __restrict__ cb, float* __restrict__ xc,
                            unsigned short* __restrict__ xcb)
{
  int idx = blockIdx.x * 256 + threadIdx.x;  // over B*L*DINNER
  int d = idx & (DINNER - 1);
  int bl = idx >> 11;
  int l = bl & (SEQL - 1);
  float s = cb[d];
  #pragma unroll
  for (int k = 0; k < 4; ++k) {
    int ll = l - 3 + k;
    if (ll >= 0) s += xz[(size_t)(bl - 3 + k) * (2 * DINNER) + d] * cw[d * 4 + k];
  }
  float r = s * sigmoidf_(s);
  xc[idx] = r;
  xcb[idx] = f2bf(r);
}

// ---------------- extract dt_raw (cols 0..63 of dbl[2048][128]) -> bf16 ----------------
__global__ void k_extract_dt(const float* __restrict__ dbl, unsigned short* __restrict__ dtraw)
{
  int idx = blockIdx.x * 256 + threadIdx.x;  // 2048*64
  int k = idx & 63;
  int rw = idx >> 6;
  dtraw[idx] = f2bf(dbl[(size_t)rw * 128 + k]);
}

// ---------------- scan pass A: per-chunk local scan, record h_end and prod(dA) ----------------
__global__ __launch_bounds__(256) void k_scan_A(
    const float* __restrict__ dtlin, const float* __restrict__ bdt,
    const float* __restrict__ xc, const float* __restrict__ dbl,
    const float* __restrict__ Alog,
    float* __restrict__ hend, float* __restrict__ aprod)
{
  int gid = blockIdx.x * 256 + threadIdx.x;  // over B*NCH*DINNER
  int d = gid & (DINNER - 1);
  int t = gid >> 11;
  int c = t & (NCH - 1);
  int b = t >> 6;
  float As[DSTATE];
  #pragma unroll
  for (int s = 0; s < DSTATE; ++s) As[s] = -__expf(Alog[d * DSTATE + s]);
  float h[DSTATE], Ap[DSTATE];
  #pragma unroll
  for (int s = 0; s < DSTATE; ++s) { h[s] = 0.f; Ap[s] = 1.f; }
  float bd = bdt[d];
  int r = b * SEQL + c * LC;
  for (int li = 0; li < LC; ++li, ++r) {
    float u = dtlin[(size_t)r * DINNER + d] + bd;
    float dt = log1pf(__expf(u));
    float xv = xc[(size_t)r * DINNER + d];
    float dtx = dt * xv;
    const float* bp = dbl + (size_t)r * 128 + 64;
    float Bv[16];
    *(float4*)&Bv[0]  = *(const float4*)(bp);
    *(float4*)&Bv[4]  = *(const float4*)(bp + 4);
    *(float4*)&Bv[8]  = *(const float4*)(bp + 8);
    *(float4*)&Bv[12] = *(const float4*)(bp + 12);
    #pragma unroll
    for (int s = 0; s < DSTATE; ++s) {
      float dA = __expf(dt * As[s]);
      h[s] = dA * h[s] + dtx * Bv[s];
      Ap[s] *= dA;
    }
  }
  size_t base = ((size_t)(b * NCH + c) * DSTATE) * DINNER + d;
  #pragma unroll
  for (int s = 0; s < DSTATE; ++s) {
    hend[base + (size_t)s * DINNER] = h[s];
    aprod[base + (size_t)s * DINNER] = Ap[s];
  }
}

// ---------------- scan pass B: sequential prefix over chunks ----------------
__global__ void k_scan_B(const float* __restrict__ hend, const float* __restrict__ aprod,
                         float* __restrict__ hin)
{
  int gid = blockIdx.x * 256 + threadIdx.x;  // B*DSTATE*DINNER = 65536
  int d = gid & (DINNER - 1);
  int s = (gid >> 11) & (DSTATE - 1);
  int b = gid >> 15;
  float h = 0.f;
  for (int c = 0; c < NCH; ++c) {
    size_t idx = ((size_t)(b * NCH + c) * DSTATE + s) * DINNER + d;
    hin[idx] = h;
    h = aprod[idx] * h + hend[idx];
  }
}

// ---------------- scan pass C: replay with correct h_in + fused epilogue ----------------
__global__ __launch_bounds__(256) void k_scan_C(
    const float* __restrict__ dtlin, const float* __restrict__ bdt,
    const float* __restrict__ xc, const float* __restrict__ dbl,
    const float* __restrict__ Alog, const float* __restrict__ hin,
    const float* __restrict__ Dskip, const float* __restrict__ xz,
    unsigned short* __restrict__ yact)
{
  int gid = blockIdx.x * 256 + threadIdx.x;
  int d = gid & (DINNER - 1);
  int t = gid >> 11;
  int c = t & (NCH - 1);
  int b = t >> 6;
  float As[DSTATE];
  #pragma unroll
  for (int s = 0; s < DSTATE; ++s) As[s] = -__expf(Alog[d * DSTATE + s]);
  float h[DSTATE];
  size_t base = ((size_t)(b * NCH + c) * DSTATE) * DINNER + d;
  #pragma unroll
  for (int s = 0; s < DSTATE; ++s) h[s] = hin[base + (size_t)s * DINNER];
  float bd = bdt[d];
  float dsk = Dskip[d];
  int r = b * SEQL + c * LC;
  for (int li = 0; li < LC; ++li, ++r) {
    float u = dtlin[(size_t)r * DINNER + d] + bd;
    float dt = log1pf(__expf(u));
    float xv = xc[(size_t)r * DINNER + d];
    float dtx = dt * xv;
    const float* bp = dbl + (size_t)r * 128 + 64;
    float Bv[16], Cv[16];
    *(float4*)&Bv[0]  = *(const float4*)(bp);
    *(float4*)&Bv[4]  = *(const float4*)(bp + 4);
    *(float4*)&Bv[8]  = *(const float4*)(bp + 8);
    *(float4*)&Bv[12] = *(const float4*)(bp + 12);
    *(float4*)&Cv[0]  = *(const float4*)(bp + 16);
    *(float4*)&Cv[4]  = *(const float4*)(bp + 20);
    *(float4*)&Cv[8]  = *(const float4*)(bp + 24);
    *(float4*)&Cv[12] = *(const float4*)(bp + 28);
    float y = 0.f;
    #pragma unroll
    for (int s = 0; s < DSTATE; ++s) {
      float dA = __expf(dt * As[s]);
      h[s] = dA * h[s] + dtx * Bv[s];
      y += h[s] * Cv[s];
    }
    y += xv * dsk;
    float zv = xz[(size_t)r * (2 * DINNER) + DINNER + d];
    float ya = y * (zv * sigmoidf_(zv));
    yact[(size_t)r * DINNER + d] = f2bf(ya);
  }
}

extern "C" void kernel_launch(void* const* d_in, const int* in_sizes, int n_in,
                              void* d_out, int out_size, void* d_ws, size_t ws_size,
                              hipStream_t stream) {
  const float* x     = (const float*)d_in[0];
  const float* Win   = (const float*)d_in[1];
  const float* cw    = (const float*)d_in[2];
  const float* cbias = (const float*)d_in[3];
  const float* Wx    = (const float*)d_in[4];
  const float* Wdt   = (const float*)d_in[5];
  const float* bdt   = (const float*)d_in[6];
  const float* Alog  = (const float*)d_in[7];
  const float* Dsk   = (const float*)d_in[8];
  const float* Wout  = (const float*)d_in[9];
  float* out = (float*)d_out;

  char* ws = (char*)d_ws;
  size_t o = 0;
  auto alloc = [&](size_t bytes) { char* p = ws + o; o += (bytes + 255) & ~(size_t)255; return p; };
  float*          xz    = (float*)         alloc((size_t)2048 * 4096 * 4);
  unsigned short* xbf   = (unsigned short*)alloc((size_t)2048 * 1024 * 2);
  unsigned short* wint  = (unsigned short*)alloc((size_t)4096 * 1024 * 2);
  float*          xc    = (float*)         alloc((size_t)2048 * 2048 * 4);
  unsigned short* xcb   = (unsigned short*)alloc((size_t)2048 * 2048 * 2);
  unsigned short* wxt   = (unsigned short*)alloc((size_t)128  * 2048 * 2);
  float*          dbl   = (float*)         alloc((size_t)2048 * 128  * 4);
  unsigned short* dtraw = (unsigned short*)alloc((size_t)2048 * 64   * 2);
  unsigned short* wdtt  = (unsigned short*)alloc((size_t)2048 * 64   * 2);
  float*          dtlin = (float*)         alloc((size_t)2048 * 2048 * 4);
  float*          hend  = (float*)         alloc((size_t)2 * NCH * DSTATE * DINNER * 4);
  float*          aprod = (float*)         alloc((size_t)2 * NCH * DSTATE * DINNER * 4);
  float*          hin   = (float*)         alloc((size_t)2 * NCH * DSTATE * DINNER * 4);
  unsigned short* yact  = (unsigned short*)alloc((size_t)2048 * 2048 * 2);
  unsigned short* woutt = (unsigned short*)alloc((size_t)1024 * 2048 * 2);
  (void)ws_size; (void)in_sizes; (void)n_in; (void)out_size;

  // convert x -> bf16
  k_f32_to_bf16<<<2048, 256, 0, stream>>>(x, xbf, 2048 * 1024);
  // transpose+convert weights
  k_transpose_bf16<<<dim3(64, 16), 256, 0, stream>>>(Win,  wint,  1024, 4096);  // [4096][1024]
  k_transpose_bf16<<<dim3(16, 32), 256, 0, stream>>>(Wout, woutt, 2048, 1024);  // [1024][2048]
  k_transpose_bf16<<<dim3(32, 1),  256, 0, stream>>>(Wdt,  wdtt,  64,   2048);  // [2048][64]
  k_wx_pad_t<<<1024, 256, 0, stream>>>(Wx, wxt);                                // [128][2048]

  // GEMM1: xz = x @ W_in   (M=2048, N=4096, K=1024)
  k_gemm_mfma<<<dim3(16, 32, 1), 256, 0, stream>>>(xbf, wint, xz, 2048, 4096, 1024);
  // conv + SiLU
  k_conv_silu<<<16384, 256, 0, stream>>>(xz, cw, cbias, xc, xcb);
  // GEMM2: dbl = xc @ W_x_pad  (M=2048, N=128, K=2048), split-K=8
  hipMemsetAsync(dbl, 0, (size_t)2048 * 128 * 4, stream);
  k_gemm_mfma<<<dim3(16, 1, 8), 256, 0, stream>>>(xcb, wxt, dbl, 2048, 128, 2048);
  // dt_raw extract
  k_extract_dt<<<512, 256, 0, stream>>>(dbl, dtraw);
  // GEMM3: dtlin = dt_raw @ W_dt  (M=2048, N=2048, K=64)
  k_gemm_mfma<<<dim3(16, 16, 1), 256, 0, stream>>>(dtraw, wdtt, dtlin, 2048, 2048, 64);
  // chunked scan
  k_scan_A<<<1024, 256, 0, stream>>>(dtlin, bdt, xc, dbl, Alog, hend, aprod);
  k_scan_B<<<256, 256, 0, stream>>>(hend, aprod, hin);
  k_scan_C<<<1024, 256, 0, stream>>>(dtlin, bdt, xc, dbl, Alog, hin, Dsk, xz, yact);
  // GEMM5: out = y_act @ W_out  (M=2048, N=1024, K=2048), split-K=2
  hipMemsetAsync(out, 0, (size_t)2048 * 1024 * 4, stream);
  k_gemm_mfma<<<dim3(16, 8, 2), 256, 0, stream>>>(yact, woutt, out, 2048, 1024, 2048);
}